// Round 2
// baseline (1675.245 us; speedup 1.0000x reference)
//
#include <hip/hip_runtime.h>
#include <hip/hip_bf16.h>

#define N_NODES_C 100000
#define N_EDGES_C 1600000
#define HID 128
#define OUTD 8
#define N_GRAPHS_C 128
#define NT 8  // nodes per block in layer kernel

static inline size_t align_up(size_t x, size_t a) { return (x + a - 1) & ~(a - 1); }

__global__ void k_zero_counts(int* __restrict__ counts, int n) {
    int i = blockIdx.x * blockDim.x + threadIdx.x;
    if (i < n) counts[i] = 0;
}

__global__ void k_count(const int* __restrict__ dst, int* __restrict__ counts) {
    int stride = gridDim.x * blockDim.x;
    for (int e = blockIdx.x * blockDim.x + threadIdx.x; e < N_EDGES_C; e += stride)
        atomicAdd(&counts[dst[e]], 1);
}

// per-block (256-wide) exclusive scan of counts; writes excl into offsets, block sums into partials
__global__ void k_scan1(const int* __restrict__ counts, int* __restrict__ offsets,
                        int* __restrict__ partials) {
    __shared__ int s[256];
    int tid = threadIdx.x;
    int i = blockIdx.x * 256 + tid;
    int v = (i < N_NODES_C) ? counts[i] : 0;
    s[tid] = v;
    __syncthreads();
    for (int off = 1; off < 256; off <<= 1) {
        int t = (tid >= off) ? s[tid - off] : 0;
        __syncthreads();
        s[tid] += t;
        __syncthreads();
    }
    if (i < N_NODES_C) offsets[i] = s[tid] - v;  // exclusive within block
    if (tid == 255) partials[blockIdx.x] = s[255];
}

// single-block exclusive scan of partials (nb <= 512)
__global__ void k_scan2(int* __restrict__ partials, int nb) {
    __shared__ int s[512];
    int tid = threadIdx.x;
    int v = (tid < nb) ? partials[tid] : 0;
    s[tid] = v;
    __syncthreads();
    for (int off = 1; off < 512; off <<= 1) {
        int t = (tid >= off) ? s[tid - off] : 0;
        __syncthreads();
        s[tid] += t;
        __syncthreads();
    }
    if (tid < nb) partials[tid] = s[tid] - v;  // exclusive
}

__global__ void k_scan3(int* __restrict__ offsets, const int* __restrict__ partials,
                        int* __restrict__ cursor) {
    int i = blockIdx.x * blockDim.x + threadIdx.x;
    if (i < N_NODES_C) {
        int o = offsets[i] + partials[i >> 8];
        offsets[i] = o;
        cursor[i] = o;
    }
    if (i == 0) offsets[N_NODES_C] = N_EDGES_C;
}

__global__ void k_fill(const int* __restrict__ src, const int* __restrict__ dst,
                       int* __restrict__ cursor, int* __restrict__ es) {
    int stride = gridDim.x * blockDim.x;
    for (int e = blockIdx.x * blockDim.x + threadIdx.x; e < N_EDGES_C; e += stride) {
        int d = dst[e];
        int pos = atomicAdd(&cursor[d], 1);
        es[pos] = src[e];
    }
}

// Fused GraphConv layer: h_out = atan(agg @ W_rel + b_rel + h_in @ W_root)
__global__ __launch_bounds__(256) void k_layer(
    const float* __restrict__ h_in, float* __restrict__ h_out,
    const int* __restrict__ offsets, const int* __restrict__ es,
    const float* __restrict__ W_rel, const float* __restrict__ b_rel,
    const float* __restrict__ W_root) {
    __shared__ float agg_l[NT][HID];
    __shared__ float h_l[NT][HID];
    const int j = threadIdx.x & 127;
    const int sub = threadIdx.x >> 7;  // 0..1
    const int node0 = blockIdx.x * NT;

    // gather-sum aggregation + stage h rows
    for (int il = sub; il < NT; il += 2) {
        int node = node0 + il;
        int beg = offsets[node];
        int end = offsets[node + 1];
        float acc = 0.f;
        for (int e = beg; e < end; ++e) {
            int sidx = es[e];  // broadcast across lanes
            acc += h_in[(size_t)sidx * HID + j];
        }
        agg_l[il][j] = acc;
        h_l[il][j] = h_in[(size_t)node * HID + j];
    }
    __syncthreads();

    // two fused 128x128 matvecs per node, 4 nodes per thread
    const int i0 = sub, i1 = sub + 2, i2 = sub + 4, i3 = sub + 6;
    float a0 = 0.f, a1 = 0.f, a2 = 0.f, a3 = 0.f;
#pragma unroll 4
    for (int k = 0; k < HID; ++k) {
        float wr = W_rel[k * HID + j];
        float wo = W_root[k * HID + j];
        a0 += agg_l[i0][k] * wr + h_l[i0][k] * wo;
        a1 += agg_l[i1][k] * wr + h_l[i1][k] * wo;
        a2 += agg_l[i2][k] * wr + h_l[i2][k] * wo;
        a3 += agg_l[i3][k] * wr + h_l[i3][k] * wo;
    }
    float bb = b_rel[j];
    h_out[(size_t)(node0 + i0) * HID + j] = atanf(a0 + bb);
    h_out[(size_t)(node0 + i1) * HID + j] = atanf(a1 + bb);
    h_out[(size_t)(node0 + i2) * HID + j] = atanf(a2 + bb);
    h_out[(size_t)(node0 + i3) * HID + j] = atanf(a3 + bb);
}

// Per-graph sum-pool + output head (sigmoid(pooled @ W_out + b_out))
__global__ __launch_bounds__(256) void k_pool_head(
    const float* __restrict__ h, const int* __restrict__ batch,
    const float* __restrict__ W_out, const float* __restrict__ b_out,
    float* __restrict__ out) {
    __shared__ float s[2][HID];
    __shared__ float sf[HID];
    const int g = blockIdx.x;
    const int j = threadIdx.x & 127;
    const int part = threadIdx.x >> 7;

    // binary search range [start, end) of graph g in sorted batch
    int lo = 0, hi = N_NODES_C;
    while (lo < hi) { int mid = (lo + hi) >> 1; if (batch[mid] < g) lo = mid + 1; else hi = mid; }
    int start = lo;
    hi = N_NODES_C;
    while (lo < hi) { int mid = (lo + hi) >> 1; if (batch[mid] < g + 1) lo = mid + 1; else hi = mid; }
    int end = lo;

    float acc = 0.f;
    for (int i = start + part; i < end; i += 2) acc += h[(size_t)i * HID + j];
    s[part][j] = acc;
    __syncthreads();
    if (threadIdx.x < HID) sf[j] = s[0][j] + s[1][j];
    __syncthreads();
    if (threadIdx.x < OUTD) {
        int o = threadIdx.x;
        float a = b_out[o];
        for (int k = 0; k < HID; ++k) a += sf[k] * W_out[k * OUTD + o];
        out[g * OUTD + o] = 1.f / (1.f + expf(-a));  // overflow-safe: expf->inf gives 0
    }
}

extern "C" void kernel_launch(void* const* d_in, const int* in_sizes, int n_in,
                              void* d_out, int out_size, void* d_ws, size_t ws_size,
                              hipStream_t stream) {
    const float* x      = (const float*)d_in[0];
    const int*   ei     = (const int*)d_in[1];
    const int*   src    = ei;
    const int*   dst    = ei + N_EDGES_C;
    const int*   batch  = (const int*)d_in[2];
    const float* W_rel  = (const float*)d_in[3];
    const float* b_rel  = (const float*)d_in[4];
    const float* W_root = (const float*)d_in[5];
    const float* W_out  = (const float*)d_in[6];
    const float* b_out  = (const float*)d_in[7];
    float* out = (float*)d_out;

    char* ws = (char*)d_ws;
    size_t off = 0;
    auto alloc = [&](size_t bytes) { void* p = ws + off; off = align_up(off + bytes, 256); return p; };
    float* hA      = (float*)alloc((size_t)N_NODES_C * HID * sizeof(float));
    float* hB      = (float*)alloc((size_t)N_NODES_C * HID * sizeof(float));
    int*   offsets = (int*)alloc((size_t)(N_NODES_C + 1) * sizeof(int));
    int*   cursor  = (int*)alloc((size_t)N_NODES_C * sizeof(int));  // doubles as counts
    int*   partials= (int*)alloc(512 * sizeof(int));
    int*   es      = (int*)alloc((size_t)N_EDGES_C * sizeof(int));

    const int nb_nodes = (N_NODES_C + 255) / 256;  // 391

    // ---- CSR build (counts live in `cursor`) ----
    k_zero_counts<<<nb_nodes, 256, 0, stream>>>(cursor, N_NODES_C);
    k_count<<<2048, 256, 0, stream>>>(dst, cursor);
    k_scan1<<<nb_nodes, 256, 0, stream>>>(cursor, offsets, partials);
    k_scan2<<<1, 512, 0, stream>>>(partials, nb_nodes);
    k_scan3<<<nb_nodes, 256, 0, stream>>>(offsets, partials, cursor);
    k_fill<<<2048, 256, 0, stream>>>(src, dst, cursor, es);

    // ---- 3 GraphConv layers ----
    const int layer_blocks = N_NODES_C / NT;  // 12500
    const int WSZ = HID * HID;
    k_layer<<<layer_blocks, 256, 0, stream>>>(x,  hA, offsets, es,
                                              W_rel + 0 * WSZ, b_rel + 0 * HID, W_root + 0 * WSZ);
    k_layer<<<layer_blocks, 256, 0, stream>>>(hA, hB, offsets, es,
                                              W_rel + 1 * WSZ, b_rel + 1 * HID, W_root + 1 * WSZ);
    k_layer<<<layer_blocks, 256, 0, stream>>>(hB, hA, offsets, es,
                                              W_rel + 2 * WSZ, b_rel + 2 * HID, W_root + 2 * WSZ);

    // ---- pool + head ----
    k_pool_head<<<N_GRAPHS_C, 256, 0, stream>>>(hA, batch, W_out, b_out, out);
}

// Round 4
// 929.751 us; speedup vs baseline: 1.8018x; 1.8018x over previous
//
#include <hip/hip_runtime.h>
#include <hip/hip_bf16.h>

#define N_NODES_C 100000
#define N_EDGES_C 1600000
#define HID 128
#define OUTD 8
#define N_GRAPHS_C 128
#define NT 32  // nodes per block in layer kernel

typedef __attribute__((ext_vector_type(4))) float f4;

static inline size_t align_up(size_t x, size_t a) { return (x + a - 1) & ~(a - 1); }

__global__ void k_zero_counts(int* __restrict__ counts, int n) {
    int i = blockIdx.x * blockDim.x + threadIdx.x;
    if (i < n) counts[i] = 0;
}

__global__ void k_count(const int* __restrict__ dst, int* __restrict__ counts) {
    int stride = gridDim.x * blockDim.x;
    for (int e = blockIdx.x * blockDim.x + threadIdx.x; e < N_EDGES_C; e += stride)
        atomicAdd(&counts[dst[e]], 1);
}

// per-block (256-wide) exclusive scan of counts; writes excl into offsets, block sums into partials
__global__ void k_scan1(const int* __restrict__ counts, int* __restrict__ offsets,
                        int* __restrict__ partials) {
    __shared__ int s[256];
    int tid = threadIdx.x;
    int i = blockIdx.x * 256 + tid;
    int v = (i < N_NODES_C) ? counts[i] : 0;
    s[tid] = v;
    __syncthreads();
    for (int off = 1; off < 256; off <<= 1) {
        int t = (tid >= off) ? s[tid - off] : 0;
        __syncthreads();
        s[tid] += t;
        __syncthreads();
    }
    if (i < N_NODES_C) offsets[i] = s[tid] - v;  // exclusive within block
    if (tid == 255) partials[blockIdx.x] = s[255];
}

// single-block exclusive scan of partials (nb <= 512)
__global__ void k_scan2(int* __restrict__ partials, int nb) {
    __shared__ int s[512];
    int tid = threadIdx.x;
    int v = (tid < nb) ? partials[tid] : 0;
    s[tid] = v;
    __syncthreads();
    for (int off = 1; off < 512; off <<= 1) {
        int t = (tid >= off) ? s[tid - off] : 0;
        __syncthreads();
        s[tid] += t;
        __syncthreads();
    }
    if (tid < nb) partials[tid] = s[tid] - v;  // exclusive
}

__global__ void k_scan3(int* __restrict__ offsets, const int* __restrict__ partials,
                        int* __restrict__ cursor) {
    int i = blockIdx.x * blockDim.x + threadIdx.x;
    if (i < N_NODES_C) {
        int o = offsets[i] + partials[i >> 8];
        offsets[i] = o;
        cursor[i] = o;
    }
    if (i == 0) offsets[N_NODES_C] = N_EDGES_C;
}

__global__ void k_fill(const int* __restrict__ src, const int* __restrict__ dst,
                       int* __restrict__ cursor, int* __restrict__ es) {
    int stride = gridDim.x * blockDim.x;
    for (int e = blockIdx.x * blockDim.x + threadIdx.x; e < N_EDGES_C; e += stride) {
        int d = dst[e];
        int pos = atomicAdd(&cursor[d], 1);
        es[pos] = src[e];
    }
}

// Fused GraphConv layer: h_out = atan(agg @ W_rel + b_rel + h_in @ W_root)
// Phase 1: gather-sum (float4 lanes, 4-way ILP). Phase 2: 4x4 register-tiled dual matvec.
__global__ __launch_bounds__(256) void k_layer(
    const float* __restrict__ h_in, float* __restrict__ h_out,
    const int* __restrict__ offsets, const int* __restrict__ es,
    const float* __restrict__ W_rel, const float* __restrict__ b_rel,
    const float* __restrict__ W_root) {
    __shared__ float agg_l[NT][HID];
    __shared__ float h_l[NT][HID];
    const int tid = threadIdx.x;
    const int node0 = blockIdx.x * NT;

    // ---- Phase 1: gather ----
    {
        const int g = tid >> 5;        // 0..7 row-groups
        const int lane = tid & 31;     // float4 chunk index
        const int c4 = lane * 4;       // float offset within row
        for (int ni = g; ni < NT; ni += 8) {
            const int node = node0 + ni;
            const int beg = offsets[node];
            const int end = offsets[node + 1];
            f4 a0 = {0.f, 0.f, 0.f, 0.f}, a1 = a0, a2 = a0, a3 = a0;
            int e = beg;
            for (; e + 4 <= end; e += 4) {
                int s0 = es[e], s1 = es[e + 1], s2 = es[e + 2], s3 = es[e + 3];
                a0 += *(const f4*)(h_in + (size_t)s0 * HID + c4);
                a1 += *(const f4*)(h_in + (size_t)s1 * HID + c4);
                a2 += *(const f4*)(h_in + (size_t)s2 * HID + c4);
                a3 += *(const f4*)(h_in + (size_t)s3 * HID + c4);
            }
            for (; e < end; ++e)
                a0 += *(const f4*)(h_in + (size_t)es[e] * HID + c4);
            *(f4*)&agg_l[ni][c4] = (a0 + a1) + (a2 + a3);
            *(f4*)&h_l[ni][c4] = *(const f4*)(h_in + (size_t)node * HID + c4);
        }
    }
    __syncthreads();

    // ---- Phase 2: C[32][128] = atan(agg@W_rel + b + h@W_root), 4 nodes x 4 j per thread ----
    {
        const int jt = tid & 31;       // j-tile
        const int it = tid >> 5;       // node-tile 0..7
        const int j0 = jt * 4;
        const int i0 = it * 4;
        f4 acc0 = {0.f, 0.f, 0.f, 0.f}, acc1 = acc0, acc2 = acc0, acc3 = acc0;
        for (int k4 = 0; k4 < HID; k4 += 4) {
            const f4 A0 = *(const f4*)&agg_l[i0 + 0][k4];
            const f4 A1 = *(const f4*)&agg_l[i0 + 1][k4];
            const f4 A2 = *(const f4*)&agg_l[i0 + 2][k4];
            const f4 A3 = *(const f4*)&agg_l[i0 + 3][k4];
            const f4 H0 = *(const f4*)&h_l[i0 + 0][k4];
            const f4 H1 = *(const f4*)&h_l[i0 + 1][k4];
            const f4 H2 = *(const f4*)&h_l[i0 + 2][k4];
            const f4 H3 = *(const f4*)&h_l[i0 + 3][k4];
#pragma unroll
            for (int kk = 0; kk < 4; ++kk) {
                const int k = k4 + kk;
                const f4 wr = *(const f4*)&W_rel[k * HID + j0];
                const f4 wo = *(const f4*)&W_root[k * HID + j0];
                acc0 += A0[kk] * wr + H0[kk] * wo;
                acc1 += A1[kk] * wr + H1[kk] * wo;
                acc2 += A2[kk] * wr + H2[kk] * wo;
                acc3 += A3[kk] * wr + H3[kk] * wo;
            }
        }
        const f4 b4 = *(const f4*)&b_rel[j0];
        acc0 += b4; acc1 += b4; acc2 += b4; acc3 += b4;
        f4 r0, r1, r2, r3;
#pragma unroll
        for (int c = 0; c < 4; ++c) {
            r0[c] = atanf(acc0[c]);
            r1[c] = atanf(acc1[c]);
            r2[c] = atanf(acc2[c]);
            r3[c] = atanf(acc3[c]);
        }
        *(f4*)&h_out[(size_t)(node0 + i0 + 0) * HID + j0] = r0;
        *(f4*)&h_out[(size_t)(node0 + i0 + 1) * HID + j0] = r1;
        *(f4*)&h_out[(size_t)(node0 + i0 + 2) * HID + j0] = r2;
        *(f4*)&h_out[(size_t)(node0 + i0 + 3) * HID + j0] = r3;
    }
}

// Per-graph sum-pool + output head (sigmoid(pooled @ W_out + b_out))
__global__ __launch_bounds__(256) void k_pool_head(
    const float* __restrict__ h, const int* __restrict__ batch,
    const float* __restrict__ W_out, const float* __restrict__ b_out,
    float* __restrict__ out) {
    __shared__ float s[2][HID];
    __shared__ float sf[HID];
    const int g = blockIdx.x;
    const int j = threadIdx.x & 127;
    const int part = threadIdx.x >> 7;

    // binary search range [start, end) of graph g in sorted batch
    int lo = 0, hi = N_NODES_C;
    while (lo < hi) { int mid = (lo + hi) >> 1; if (batch[mid] < g) lo = mid + 1; else hi = mid; }
    int start = lo;
    hi = N_NODES_C;
    while (lo < hi) { int mid = (lo + hi) >> 1; if (batch[mid] < g + 1) lo = mid + 1; else hi = mid; }
    int end = lo;

    float acc = 0.f;
    for (int i = start + part; i < end; i += 2) acc += h[(size_t)i * HID + j];
    s[part][j] = acc;
    __syncthreads();
    if (threadIdx.x < HID) sf[j] = s[0][j] + s[1][j];
    __syncthreads();
    if (threadIdx.x < OUTD) {
        int o = threadIdx.x;
        float a = b_out[o];
        for (int k = 0; k < HID; ++k) a += sf[k] * W_out[k * OUTD + o];
        out[g * OUTD + o] = 1.f / (1.f + expf(-a));  // overflow-safe
    }
}

extern "C" void kernel_launch(void* const* d_in, const int* in_sizes, int n_in,
                              void* d_out, int out_size, void* d_ws, size_t ws_size,
                              hipStream_t stream) {
    const float* x      = (const float*)d_in[0];
    const int*   ei     = (const int*)d_in[1];
    const int*   src    = ei;
    const int*   dst    = ei + N_EDGES_C;
    const int*   batch  = (const int*)d_in[2];
    const float* W_rel  = (const float*)d_in[3];
    const float* b_rel  = (const float*)d_in[4];
    const float* W_root = (const float*)d_in[5];
    const float* W_out  = (const float*)d_in[6];
    const float* b_out  = (const float*)d_in[7];
    float* out = (float*)d_out;

    char* ws = (char*)d_ws;
    size_t off = 0;
    auto alloc = [&](size_t bytes) { void* p = ws + off; off = align_up(off + bytes, 256); return p; };
    float* hA      = (float*)alloc((size_t)N_NODES_C * HID * sizeof(float));
    float* hB      = (float*)alloc((size_t)N_NODES_C * HID * sizeof(float));
    int*   offsets = (int*)alloc((size_t)(N_NODES_C + 1) * sizeof(int));
    int*   cursor  = (int*)alloc((size_t)N_NODES_C * sizeof(int));  // doubles as counts
    int*   partials= (int*)alloc(512 * sizeof(int));
    int*   es      = (int*)alloc((size_t)N_EDGES_C * sizeof(int));

    const int nb_nodes = (N_NODES_C + 255) / 256;  // 391

    // ---- CSR build (counts live in `cursor`) ----
    k_zero_counts<<<nb_nodes, 256, 0, stream>>>(cursor, N_NODES_C);
    k_count<<<2048, 256, 0, stream>>>(dst, cursor);
    k_scan1<<<nb_nodes, 256, 0, stream>>>(cursor, offsets, partials);
    k_scan2<<<1, 512, 0, stream>>>(partials, nb_nodes);
    k_scan3<<<nb_nodes, 256, 0, stream>>>(offsets, partials, cursor);
    k_fill<<<2048, 256, 0, stream>>>(src, dst, cursor, es);

    // ---- 3 GraphConv layers ----
    const int layer_blocks = N_NODES_C / NT;  // 3125
    const int WSZ = HID * HID;
    k_layer<<<layer_blocks, 256, 0, stream>>>(x,  hA, offsets, es,
                                              W_rel + 0 * WSZ, b_rel + 0 * HID, W_root + 0 * WSZ);
    k_layer<<<layer_blocks, 256, 0, stream>>>(hA, hB, offsets, es,
                                              W_rel + 1 * WSZ, b_rel + 1 * HID, W_root + 1 * WSZ);
    k_layer<<<layer_blocks, 256, 0, stream>>>(hB, hA, offsets, es,
                                              W_rel + 2 * WSZ, b_rel + 2 * HID, W_root + 2 * WSZ);

    // ---- pool + head ----
    k_pool_head<<<N_GRAPHS_C, 256, 0, stream>>>(hA, batch, W_out, b_out, out);
}

// Round 6
// 860.006 us; speedup vs baseline: 1.9479x; 1.0811x over previous
//
#include <hip/hip_runtime.h>
#include <hip/hip_bf16.h>

#define N_NODES_C 100000
#define N_EDGES_C 1600000
#define HID 128
#define OUTD 8
#define N_GRAPHS_C 128
#define NT 32   // nodes per block in layer kernel
#define KCH 16  // k-chunk staged in LDS for W
#define SEG 8   // pool segments per graph

typedef __attribute__((ext_vector_type(4))) float f4;

static inline size_t align_up(size_t x, size_t a) { return (x + a - 1) & ~(a - 1); }

__global__ void k_zero_counts(int* __restrict__ counts, int n) {
    int i = blockIdx.x * blockDim.x + threadIdx.x;
    if (i < n) counts[i] = 0;
}

__global__ void k_count(const int* __restrict__ dst, int* __restrict__ counts) {
    int stride = gridDim.x * blockDim.x;
    for (int e = blockIdx.x * blockDim.x + threadIdx.x; e < N_EDGES_C; e += stride)
        atomicAdd(&counts[dst[e]], 1);
}

__global__ void k_scan1(const int* __restrict__ counts, int* __restrict__ offsets,
                        int* __restrict__ partials) {
    __shared__ int s[256];
    int tid = threadIdx.x;
    int i = blockIdx.x * 256 + tid;
    int v = (i < N_NODES_C) ? counts[i] : 0;
    s[tid] = v;
    __syncthreads();
    for (int off = 1; off < 256; off <<= 1) {
        int t = (tid >= off) ? s[tid - off] : 0;
        __syncthreads();
        s[tid] += t;
        __syncthreads();
    }
    if (i < N_NODES_C) offsets[i] = s[tid] - v;
    if (tid == 255) partials[blockIdx.x] = s[255];
}

__global__ void k_scan2(int* __restrict__ partials, int nb) {
    __shared__ int s[512];
    int tid = threadIdx.x;
    int v = (tid < nb) ? partials[tid] : 0;
    s[tid] = v;
    __syncthreads();
    for (int off = 1; off < 512; off <<= 1) {
        int t = (tid >= off) ? s[tid - off] : 0;
        __syncthreads();
        s[tid] += t;
        __syncthreads();
    }
    if (tid < nb) partials[tid] = s[tid] - v;
}

__global__ void k_scan3(int* __restrict__ offsets, const int* __restrict__ partials,
                        int* __restrict__ cursor) {
    int i = blockIdx.x * blockDim.x + threadIdx.x;
    if (i < N_NODES_C) {
        int o = offsets[i] + partials[i >> 8];
        offsets[i] = o;
        cursor[i] = o;
    }
    if (i == 0) offsets[N_NODES_C] = N_EDGES_C;
}

__global__ void k_fill(const int* __restrict__ src, const int* __restrict__ dst,
                       int* __restrict__ cursor, int* __restrict__ es) {
    int stride = gridDim.x * blockDim.x;
    for (int e = blockIdx.x * blockDim.x + threadIdx.x; e < N_EDGES_C; e += stride) {
        int d = dst[e];
        int pos = atomicAdd(&cursor[d], 1);
        es[pos] = src[e];
    }
}

// Fused GraphConv layer: h_out = atan(agg @ W_rel + b_rel + h_in @ W_root)
// Phase 1: gather-sum (float4 lanes, 8-way ILP).
// Phase 2: 4x4 register-tiled dual matvec, W staged in LDS per 16-k chunk.
__global__ __launch_bounds__(256) void k_layer(
    const float* __restrict__ h_in, float* __restrict__ h_out,
    const int* __restrict__ offsets, const int* __restrict__ es,
    const float* __restrict__ W_rel, const float* __restrict__ b_rel,
    const float* __restrict__ W_root) {
    __shared__ float agg_l[NT][HID];
    __shared__ float h_l[NT][HID];
    __shared__ float w_lds[2][KCH][HID];  // 16 KB
    const int tid = threadIdx.x;
    const int node0 = blockIdx.x * NT;

    // ---- Phase 1: gather (32-lane group per node row, 8 accumulators) ----
    {
        const int g = tid >> 5;
        const int lane = tid & 31;
        const int c4 = lane * 4;
        for (int ni = g; ni < NT; ni += 8) {
            const int node = node0 + ni;
            const int beg = offsets[node];
            const int end = offsets[node + 1];
            f4 a0 = {0.f, 0.f, 0.f, 0.f}, a1 = a0, a2 = a0, a3 = a0;
            f4 a4 = a0, a5 = a0, a6 = a0, a7 = a0;
            int e = beg;
            for (; e + 8 <= end; e += 8) {
                int s0 = es[e],     s1 = es[e + 1], s2 = es[e + 2], s3 = es[e + 3];
                int s4 = es[e + 4], s5 = es[e + 5], s6 = es[e + 6], s7 = es[e + 7];
                a0 += *(const f4*)(h_in + (size_t)s0 * HID + c4);
                a1 += *(const f4*)(h_in + (size_t)s1 * HID + c4);
                a2 += *(const f4*)(h_in + (size_t)s2 * HID + c4);
                a3 += *(const f4*)(h_in + (size_t)s3 * HID + c4);
                a4 += *(const f4*)(h_in + (size_t)s4 * HID + c4);
                a5 += *(const f4*)(h_in + (size_t)s5 * HID + c4);
                a6 += *(const f4*)(h_in + (size_t)s6 * HID + c4);
                a7 += *(const f4*)(h_in + (size_t)s7 * HID + c4);
            }
            for (; e + 4 <= end; e += 4) {
                int s0 = es[e], s1 = es[e + 1], s2 = es[e + 2], s3 = es[e + 3];
                a0 += *(const f4*)(h_in + (size_t)s0 * HID + c4);
                a1 += *(const f4*)(h_in + (size_t)s1 * HID + c4);
                a2 += *(const f4*)(h_in + (size_t)s2 * HID + c4);
                a3 += *(const f4*)(h_in + (size_t)s3 * HID + c4);
            }
            for (; e < end; ++e)
                a0 += *(const f4*)(h_in + (size_t)es[e] * HID + c4);
            *(f4*)&agg_l[ni][c4] = ((a0 + a1) + (a2 + a3)) + ((a4 + a5) + (a6 + a7));
            *(f4*)&h_l[ni][c4] = *(const f4*)(h_in + (size_t)node * HID + c4);
        }
    }

    // ---- Phase 2: C[32][128] = atan(agg@W_rel + b + h@W_root) ----
    {
        const int jt = tid & 31;
        const int it = tid >> 5;  // 0..7
        const int j0 = jt * 4;
        const int i0 = it * 4;
        f4 acc0 = {0.f, 0.f, 0.f, 0.f}, acc1 = acc0, acc2 = acc0, acc3 = acc0;
        for (int kc = 0; kc < HID; kc += KCH) {
            __syncthreads();  // kc=0: phase1->2 barrier; else: protect w_lds reuse
            {   // cooperative stage of W chunk: 2 matrices x 512 f4, 4 f4/thread
                const f4* Wr = (const f4*)(W_rel + (size_t)kc * HID);
                const f4* Wo = (const f4*)(W_root + (size_t)kc * HID);
                f4* wl0 = (f4*)&w_lds[0][0][0];
                f4* wl1 = (f4*)&w_lds[1][0][0];
                wl0[tid]       = Wr[tid];
                wl0[tid + 256] = Wr[tid + 256];
                wl1[tid]       = Wo[tid];
                wl1[tid + 256] = Wo[tid + 256];
            }
            __syncthreads();
#pragma unroll
            for (int k4 = 0; k4 < KCH; k4 += 4) {
                const int kg = kc + k4;
                const f4 A0 = *(const f4*)&agg_l[i0 + 0][kg];
                const f4 A1 = *(const f4*)&agg_l[i0 + 1][kg];
                const f4 A2 = *(const f4*)&agg_l[i0 + 2][kg];
                const f4 A3 = *(const f4*)&agg_l[i0 + 3][kg];
                const f4 H0 = *(const f4*)&h_l[i0 + 0][kg];
                const f4 H1 = *(const f4*)&h_l[i0 + 1][kg];
                const f4 H2 = *(const f4*)&h_l[i0 + 2][kg];
                const f4 H3 = *(const f4*)&h_l[i0 + 3][kg];
#pragma unroll
                for (int kk = 0; kk < 4; ++kk) {
                    const f4 wr = *(const f4*)&w_lds[0][k4 + kk][j0];
                    const f4 wo = *(const f4*)&w_lds[1][k4 + kk][j0];
                    acc0 += A0[kk] * wr + H0[kk] * wo;
                    acc1 += A1[kk] * wr + H1[kk] * wo;
                    acc2 += A2[kk] * wr + H2[kk] * wo;
                    acc3 += A3[kk] * wr + H3[kk] * wo;
                }
            }
        }
        const f4 b4 = *(const f4*)&b_rel[j0];
        acc0 += b4; acc1 += b4; acc2 += b4; acc3 += b4;
        f4 r0, r1, r2, r3;
#pragma unroll
        for (int c = 0; c < 4; ++c) {
            r0[c] = atanf(acc0[c]);
            r1[c] = atanf(acc1[c]);
            r2[c] = atanf(acc2[c]);
            r3[c] = atanf(acc3[c]);
        }
        *(f4*)&h_out[(size_t)(node0 + i0 + 0) * HID + j0] = r0;
        *(f4*)&h_out[(size_t)(node0 + i0 + 1) * HID + j0] = r1;
        *(f4*)&h_out[(size_t)(node0 + i0 + 2) * HID + j0] = r2;
        *(f4*)&h_out[(size_t)(node0 + i0 + 3) * HID + j0] = r3;
    }
}

// Pool stage 1: per (graph, segment) partial sums -> part[(g*SEG+s)][HID]
__global__ __launch_bounds__(256) void k_pool1(
    const float* __restrict__ h, const int* __restrict__ batch,
    float* __restrict__ part) {
    __shared__ float sm[2][HID];
    const int b = blockIdx.x;            // 0..G*SEG-1
    const int g = b >> 3, s = b & (SEG - 1);
    const int j = threadIdx.x & 127;
    const int half = threadIdx.x >> 7;

    int lo = 0, hi = N_NODES_C;
    while (lo < hi) { int mid = (lo + hi) >> 1; if (batch[mid] < g) lo = mid + 1; else hi = mid; }
    int start = lo;
    hi = N_NODES_C;
    while (lo < hi) { int mid = (lo + hi) >> 1; if (batch[mid] < g + 1) lo = mid + 1; else hi = mid; }
    int end = lo;
    int len = end - start;
    int s0 = start + (int)((long long)len * s / SEG);
    int s1 = start + (int)((long long)len * (s + 1) / SEG);

    float acc = 0.f;
    for (int i = s0 + half; i < s1; i += 2) acc += h[(size_t)i * HID + j];
    sm[half][j] = acc;
    __syncthreads();
    if (threadIdx.x < HID) part[(size_t)b * HID + j] = sm[0][j] + sm[1][j];
}

// Pool stage 2 + head: pooled = sum of SEG partials; out = sigmoid(pooled@W_out + b_out)
__global__ __launch_bounds__(128) void k_head(
    const float* __restrict__ part, const float* __restrict__ W_out,
    const float* __restrict__ b_out, float* __restrict__ out) {
    __shared__ float sf[HID];
    const int g = blockIdx.x;
    const int j = threadIdx.x;
    float v = 0.f;
    for (int s = 0; s < SEG; ++s) v += part[(size_t)(g * SEG + s) * HID + j];
    sf[j] = v;
    __syncthreads();
    if (j < OUTD) {
        float a = b_out[j];
        for (int k = 0; k < HID; ++k) a += sf[k] * W_out[k * OUTD + j];
        out[g * OUTD + j] = 1.f / (1.f + expf(-a));
    }
}

extern "C" void kernel_launch(void* const* d_in, const int* in_sizes, int n_in,
                              void* d_out, int out_size, void* d_ws, size_t ws_size,
                              hipStream_t stream) {
    const float* x      = (const float*)d_in[0];
    const int*   ei     = (const int*)d_in[1];
    const int*   src    = ei;
    const int*   dst    = ei + N_EDGES_C;
    const int*   batch  = (const int*)d_in[2];
    const float* W_rel  = (const float*)d_in[3];
    const float* b_rel  = (const float*)d_in[4];
    const float* W_root = (const float*)d_in[5];
    const float* W_out  = (const float*)d_in[6];
    const float* b_out  = (const float*)d_in[7];
    float* out = (float*)d_out;

    char* ws = (char*)d_ws;
    size_t off = 0;
    auto alloc = [&](size_t bytes) { void* p = ws + off; off = align_up(off + bytes, 256); return p; };
    float* hA      = (float*)alloc((size_t)N_NODES_C * HID * sizeof(float));
    float* hB      = (float*)alloc((size_t)N_NODES_C * HID * sizeof(float));
    int*   offsets = (int*)alloc((size_t)(N_NODES_C + 1) * sizeof(int));
    int*   cursor  = (int*)alloc((size_t)N_NODES_C * sizeof(int));
    int*   partials= (int*)alloc(512 * sizeof(int));
    int*   es      = (int*)alloc((size_t)N_EDGES_C * sizeof(int));
    float* part    = (float*)alloc((size_t)N_GRAPHS_C * SEG * HID * sizeof(float));

    const int nb_nodes = (N_NODES_C + 255) / 256;  // 391

    // ---- CSR build (counts live in `cursor`) ----
    k_zero_counts<<<nb_nodes, 256, 0, stream>>>(cursor, N_NODES_C);
    k_count<<<2048, 256, 0, stream>>>(dst, cursor);
    k_scan1<<<nb_nodes, 256, 0, stream>>>(cursor, offsets, partials);
    k_scan2<<<1, 512, 0, stream>>>(partials, nb_nodes);
    k_scan3<<<nb_nodes, 256, 0, stream>>>(offsets, partials, cursor);
    k_fill<<<2048, 256, 0, stream>>>(src, dst, cursor, es);

    // ---- 3 GraphConv layers ----
    const int layer_blocks = N_NODES_C / NT;  // 3125
    const int WSZ = HID * HID;
    k_layer<<<layer_blocks, 256, 0, stream>>>(x,  hA, offsets, es,
                                              W_rel + 0 * WSZ, b_rel + 0 * HID, W_root + 0 * WSZ);
    k_layer<<<layer_blocks, 256, 0, stream>>>(hA, hB, offsets, es,
                                              W_rel + 1 * WSZ, b_rel + 1 * HID, W_root + 1 * WSZ);
    k_layer<<<layer_blocks, 256, 0, stream>>>(hB, hA, offsets, es,
                                              W_rel + 2 * WSZ, b_rel + 2 * HID, W_root + 2 * WSZ);

    // ---- pool + head ----
    k_pool1<<<N_GRAPHS_C * SEG, 256, 0, stream>>>(hA, batch, part);
    k_head<<<N_GRAPHS_C, 128, 0, stream>>>(part, W_out, b_out, out);
}

// Round 8
// 758.303 us; speedup vs baseline: 2.2092x; 1.1341x over previous
//
#include <hip/hip_runtime.h>
#include <hip/hip_bf16.h>

#define N_NODES_C 100000
#define N_EDGES_C 1600000
#define HID 128
#define OUTD 8
#define N_GRAPHS_C 128
#define NT 32   // nodes per block in layer kernel
#define SEG 8   // pool segments per graph

typedef __attribute__((ext_vector_type(4))) float f4;
typedef __attribute__((ext_vector_type(4))) _Float16 h4;

static inline size_t align_up(size_t x, size_t a) { return (x + a - 1) & ~(a - 1); }

__device__ __forceinline__ f4 h2f(h4 v) { return __builtin_convertvector(v, f4); }
__device__ __forceinline__ h4 f2h(f4 v) { return __builtin_convertvector(v, h4); }

__global__ __launch_bounds__(256) void k_cvt(const float* __restrict__ in,
                                             _Float16* __restrict__ out) {
    int i = blockIdx.x * blockDim.x + threadIdx.x;  // 3.2M threads, 4 floats each
    f4 v = *(const f4*)(in + (size_t)i * 4);
    *(h4*)(out + (size_t)i * 4) = f2h(v);
}

__global__ void k_zero_counts(int* __restrict__ counts, int n) {
    int i = blockIdx.x * blockDim.x + threadIdx.x;
    if (i < n) counts[i] = 0;
}

__global__ void k_count(const int* __restrict__ dst, int* __restrict__ counts) {
    int stride = gridDim.x * blockDim.x;
    for (int e = blockIdx.x * blockDim.x + threadIdx.x; e < N_EDGES_C; e += stride)
        atomicAdd(&counts[dst[e]], 1);
}

__global__ void k_scan1(const int* __restrict__ counts, int* __restrict__ offsets,
                        int* __restrict__ partials) {
    __shared__ int s[256];
    int tid = threadIdx.x;
    int i = blockIdx.x * 256 + tid;
    int v = (i < N_NODES_C) ? counts[i] : 0;
    s[tid] = v;
    __syncthreads();
    for (int off = 1; off < 256; off <<= 1) {
        int t = (tid >= off) ? s[tid - off] : 0;
        __syncthreads();
        s[tid] += t;
        __syncthreads();
    }
    if (i < N_NODES_C) offsets[i] = s[tid] - v;
    if (tid == 255) partials[blockIdx.x] = s[255];
}

__global__ void k_scan2(int* __restrict__ partials, int nb) {
    __shared__ int s[512];
    int tid = threadIdx.x;
    int v = (tid < nb) ? partials[tid] : 0;
    s[tid] = v;
    __syncthreads();
    for (int off = 1; off < 512; off <<= 1) {
        int t = (tid >= off) ? s[tid - off] : 0;
        __syncthreads();
        s[tid] += t;
        __syncthreads();
    }
    if (tid < nb) partials[tid] = s[tid] - v;
}

__global__ void k_scan3(int* __restrict__ offsets, const int* __restrict__ partials,
                        int* __restrict__ cursor) {
    int i = blockIdx.x * blockDim.x + threadIdx.x;
    if (i < N_NODES_C) {
        int o = offsets[i] + partials[i >> 8];
        offsets[i] = o;
        cursor[i] = o;
    }
    if (i == 0) offsets[N_NODES_C] = N_EDGES_C;
}

__global__ void k_fill(const int* __restrict__ src, const int* __restrict__ dst,
                       int* __restrict__ cursor, int* __restrict__ es) {
    int stride = gridDim.x * blockDim.x;
    for (int e = blockIdx.x * blockDim.x + threadIdx.x; e < N_EDGES_C; e += stride) {
        int d = dst[e];
        int pos = atomicAdd(&cursor[d], 1);
        es[pos] = src[e];
    }
}

// Fused GraphConv layer, fp16 h storage / fp32 compute:
//   h_out = atan(agg @ W_rel + b_rel + h_in @ W_root)
// Phase 1: fp16 gather-sum (8B lanes, 8-way ILP, fp32 accumulate).
// Phase 2: 4x4 register-tiled dual matvec, W direct from global (L1/L2-resident).
template <int OUT_F16>
__global__ __launch_bounds__(256) void k_layer(
    const _Float16* __restrict__ h_in,   // fp16 [N][HID]
    _Float16* __restrict__ h_out_h,      // fp16 out (layers 0,1)
    float* __restrict__ h_out_f,         // fp32 out (layer 2)
    const int* __restrict__ offsets, const int* __restrict__ es,
    const float* __restrict__ W_rel, const float* __restrict__ b_rel,
    const float* __restrict__ W_root) {
    __shared__ float agg_l[NT][HID];
    __shared__ float h_l[NT][HID];
    const int tid = threadIdx.x;
    const int node0 = blockIdx.x * NT;

    // ---- Phase 1: gather (32-lane group per node row, 8 accumulators) ----
    {
        const int g = tid >> 5;
        const int lane = tid & 31;
        const int c4 = lane * 4;
        for (int ni = g; ni < NT; ni += 8) {
            const int node = node0 + ni;
            const int beg = offsets[node];
            const int end = offsets[node + 1];
            f4 a0 = {0.f, 0.f, 0.f, 0.f}, a1 = a0, a2 = a0, a3 = a0;
            f4 a4 = a0, a5 = a0, a6 = a0, a7 = a0;
            int e = beg;
            for (; e + 8 <= end; e += 8) {
                int s0 = es[e],     s1 = es[e + 1], s2 = es[e + 2], s3 = es[e + 3];
                int s4 = es[e + 4], s5 = es[e + 5], s6 = es[e + 6], s7 = es[e + 7];
                h4 v0 = *(const h4*)(h_in + (size_t)s0 * HID + c4);
                h4 v1 = *(const h4*)(h_in + (size_t)s1 * HID + c4);
                h4 v2 = *(const h4*)(h_in + (size_t)s2 * HID + c4);
                h4 v3 = *(const h4*)(h_in + (size_t)s3 * HID + c4);
                h4 v4 = *(const h4*)(h_in + (size_t)s4 * HID + c4);
                h4 v5 = *(const h4*)(h_in + (size_t)s5 * HID + c4);
                h4 v6 = *(const h4*)(h_in + (size_t)s6 * HID + c4);
                h4 v7 = *(const h4*)(h_in + (size_t)s7 * HID + c4);
                a0 += h2f(v0); a1 += h2f(v1); a2 += h2f(v2); a3 += h2f(v3);
                a4 += h2f(v4); a5 += h2f(v5); a6 += h2f(v6); a7 += h2f(v7);
            }
            for (; e + 4 <= end; e += 4) {
                int s0 = es[e], s1 = es[e + 1], s2 = es[e + 2], s3 = es[e + 3];
                h4 v0 = *(const h4*)(h_in + (size_t)s0 * HID + c4);
                h4 v1 = *(const h4*)(h_in + (size_t)s1 * HID + c4);
                h4 v2 = *(const h4*)(h_in + (size_t)s2 * HID + c4);
                h4 v3 = *(const h4*)(h_in + (size_t)s3 * HID + c4);
                a0 += h2f(v0); a1 += h2f(v1); a2 += h2f(v2); a3 += h2f(v3);
            }
            for (; e < end; ++e)
                a0 += h2f(*(const h4*)(h_in + (size_t)es[e] * HID + c4));
            *(f4*)&agg_l[ni][c4] = ((a0 + a1) + (a2 + a3)) + ((a4 + a5) + (a6 + a7));
            *(f4*)&h_l[ni][c4] = h2f(*(const h4*)(h_in + (size_t)node * HID + c4));
        }
    }
    __syncthreads();

    // ---- Phase 2: C[32][128] = atan(agg@W_rel + b + h@W_root), 4 nodes x 4 j per thread ----
    {
        const int jt = tid & 31;
        const int it = tid >> 5;  // 0..7
        const int j0 = jt * 4;
        const int i0 = it * 4;
        f4 acc0 = {0.f, 0.f, 0.f, 0.f}, acc1 = acc0, acc2 = acc0, acc3 = acc0;
        for (int k4 = 0; k4 < HID; k4 += 4) {
            const f4 A0 = *(const f4*)&agg_l[i0 + 0][k4];
            const f4 A1 = *(const f4*)&agg_l[i0 + 1][k4];
            const f4 A2 = *(const f4*)&agg_l[i0 + 2][k4];
            const f4 A3 = *(const f4*)&agg_l[i0 + 3][k4];
            const f4 H0 = *(const f4*)&h_l[i0 + 0][k4];
            const f4 H1 = *(const f4*)&h_l[i0 + 1][k4];
            const f4 H2 = *(const f4*)&h_l[i0 + 2][k4];
            const f4 H3 = *(const f4*)&h_l[i0 + 3][k4];
#pragma unroll
            for (int kk = 0; kk < 4; ++kk) {
                const int k = k4 + kk;
                const f4 wr = *(const f4*)&W_rel[k * HID + j0];
                const f4 wo = *(const f4*)&W_root[k * HID + j0];
                acc0 += A0[kk] * wr + H0[kk] * wo;
                acc1 += A1[kk] * wr + H1[kk] * wo;
                acc2 += A2[kk] * wr + H2[kk] * wo;
                acc3 += A3[kk] * wr + H3[kk] * wo;
            }
        }
        const f4 b4 = *(const f4*)&b_rel[j0];
        acc0 += b4; acc1 += b4; acc2 += b4; acc3 += b4;
        f4 r0, r1, r2, r3;
#pragma unroll
        for (int c = 0; c < 4; ++c) {
            r0[c] = atanf(acc0[c]);
            r1[c] = atanf(acc1[c]);
            r2[c] = atanf(acc2[c]);
            r3[c] = atanf(acc3[c]);
        }
        if (OUT_F16) {
            *(h4*)(h_out_h + (size_t)(node0 + i0 + 0) * HID + j0) = f2h(r0);
            *(h4*)(h_out_h + (size_t)(node0 + i0 + 1) * HID + j0) = f2h(r1);
            *(h4*)(h_out_h + (size_t)(node0 + i0 + 2) * HID + j0) = f2h(r2);
            *(h4*)(h_out_h + (size_t)(node0 + i0 + 3) * HID + j0) = f2h(r3);
        } else {
            *(f4*)(h_out_f + (size_t)(node0 + i0 + 0) * HID + j0) = r0;
            *(f4*)(h_out_f + (size_t)(node0 + i0 + 1) * HID + j0) = r1;
            *(f4*)(h_out_f + (size_t)(node0 + i0 + 2) * HID + j0) = r2;
            *(f4*)(h_out_f + (size_t)(node0 + i0 + 3) * HID + j0) = r3;
        }
    }
}

// Pool stage 1: per (graph, segment) partial sums -> part[(g*SEG+s)][HID]
__global__ __launch_bounds__(256) void k_pool1(
    const float* __restrict__ h, const int* __restrict__ batch,
    float* __restrict__ part) {
    __shared__ float sm[2][HID];
    const int b = blockIdx.x;
    const int g = b >> 3, s = b & (SEG - 1);
    const int j = threadIdx.x & 127;
    const int half = threadIdx.x >> 7;

    int lo = 0, hi = N_NODES_C;
    while (lo < hi) { int mid = (lo + hi) >> 1; if (batch[mid] < g) lo = mid + 1; else hi = mid; }
    int start = lo;
    hi = N_NODES_C;
    while (lo < hi) { int mid = (lo + hi) >> 1; if (batch[mid] < g + 1) lo = mid + 1; else hi = mid; }
    int end = lo;
    int len = end - start;
    int s0 = start + (int)((long long)len * s / SEG);
    int s1 = start + (int)((long long)len * (s + 1) / SEG);

    float acc = 0.f;
    for (int i = s0 + half; i < s1; i += 2) acc += h[(size_t)i * HID + j];
    sm[half][j] = acc;
    __syncthreads();
    if (threadIdx.x < HID) part[(size_t)b * HID + j] = sm[0][j] + sm[1][j];
}

// Pool stage 2 + head
__global__ __launch_bounds__(128) void k_head(
    const float* __restrict__ part, const float* __restrict__ W_out,
    const float* __restrict__ b_out, float* __restrict__ out) {
    __shared__ float sf[HID];
    const int g = blockIdx.x;
    const int j = threadIdx.x;
    float v = 0.f;
    for (int s = 0; s < SEG; ++s) v += part[(size_t)(g * SEG + s) * HID + j];
    sf[j] = v;
    __syncthreads();
    if (j < OUTD) {
        float a = b_out[j];
        for (int k = 0; k < HID; ++k) a += sf[k] * W_out[k * OUTD + j];
        out[g * OUTD + j] = 1.f / (1.f + expf(-a));
    }
}

extern "C" void kernel_launch(void* const* d_in, const int* in_sizes, int n_in,
                              void* d_out, int out_size, void* d_ws, size_t ws_size,
                              hipStream_t stream) {
    const float* x      = (const float*)d_in[0];
    const int*   ei     = (const int*)d_in[1];
    const int*   src    = ei;
    const int*   dst    = ei + N_EDGES_C;
    const int*   batch  = (const int*)d_in[2];
    const float* W_rel  = (const float*)d_in[3];
    const float* b_rel  = (const float*)d_in[4];
    const float* W_root = (const float*)d_in[5];
    const float* W_out  = (const float*)d_in[6];
    const float* b_out  = (const float*)d_in[7];
    float* out = (float*)d_out;

    char* ws = (char*)d_ws;
    size_t off = 0;
    auto alloc = [&](size_t bytes) { void* p = ws + off; off = align_up(off + bytes, 256); return p; };
    _Float16* xh  = (_Float16*)alloc((size_t)N_NODES_C * HID * 2);  // fp16; reused as h2
    _Float16* h1h = (_Float16*)alloc((size_t)N_NODES_C * HID * 2);  // fp16
    float* h3f     = (float*)alloc((size_t)N_NODES_C * HID * sizeof(float));
    int*   offsets = (int*)alloc((size_t)(N_NODES_C + 1) * sizeof(int));
    int*   cursor  = (int*)alloc((size_t)N_NODES_C * sizeof(int));
    int*   partials= (int*)alloc(512 * sizeof(int));
    int*   es      = (int*)alloc((size_t)N_EDGES_C * sizeof(int));
    float* part    = (float*)alloc((size_t)N_GRAPHS_C * SEG * HID * sizeof(float));

    const int nb_nodes = (N_NODES_C + 255) / 256;  // 391

    // ---- x -> fp16 ----
    k_cvt<<<(N_NODES_C * HID) / 4 / 256, 256, 0, stream>>>(x, xh);

    // ---- CSR build (counts live in `cursor`) ----
    k_zero_counts<<<nb_nodes, 256, 0, stream>>>(cursor, N_NODES_C);
    k_count<<<2048, 256, 0, stream>>>(dst, cursor);
    k_scan1<<<nb_nodes, 256, 0, stream>>>(cursor, offsets, partials);
    k_scan2<<<1, 512, 0, stream>>>(partials, nb_nodes);
    k_scan3<<<nb_nodes, 256, 0, stream>>>(offsets, partials, cursor);
    k_fill<<<2048, 256, 0, stream>>>(src, dst, cursor, es);

    // ---- 3 GraphConv layers (fp16 h chain, fp32 final) ----
    const int layer_blocks = N_NODES_C / NT;  // 3125
    const int WSZ = HID * HID;
    k_layer<1><<<layer_blocks, 256, 0, stream>>>(xh,  h1h, nullptr, offsets, es,
                                                 W_rel + 0 * WSZ, b_rel + 0 * HID, W_root + 0 * WSZ);
    k_layer<1><<<layer_blocks, 256, 0, stream>>>(h1h, xh,  nullptr, offsets, es,
                                                 W_rel + 1 * WSZ, b_rel + 1 * HID, W_root + 1 * WSZ);
    k_layer<0><<<layer_blocks, 256, 0, stream>>>(xh,  nullptr, h3f, offsets, es,
                                                 W_rel + 2 * WSZ, b_rel + 2 * HID, W_root + 2 * WSZ);

    // ---- pool + head ----
    k_pool1<<<N_GRAPHS_C * SEG, 256, 0, stream>>>(h3f, batch, part);
    k_head<<<N_GRAPHS_C, 128, 0, stream>>>(part, W_out, b_out, out);
}